// Round 14
// baseline (284.476 us; speedup 1.0000x reference)
//
#include <hip/hip_runtime.h>
#include <hip/hip_bf16.h>

#define SEQ   2048
#define HDIM  2048
#define NHEAD 16
#define HEADD 128
#define BATCH 2
#define MTOT  (BATCH*SEQ)   // 4096
#define BH    (BATCH*NHEAD) // 32

typedef __attribute__((ext_vector_type(8))) __bf16 bf16x8;
typedef __attribute__((ext_vector_type(4))) float f32x4;
typedef __attribute__((ext_vector_type(16))) float f32x16;
typedef __attribute__((ext_vector_type(8))) unsigned short u16x8;

__device__ __forceinline__ unsigned short f2b(float f) {
    __bf16 h = (__bf16)f;
    return __builtin_bit_cast(unsigned short, h);
}

__device__ __forceinline__ void gld_lds16(const void* gptr, void* ldsptr) {
    __builtin_amdgcn_global_load_lds(
        (const __attribute__((address_space(1))) unsigned int*)gptr,
        (__attribute__((address_space(3))) unsigned int*)ldsptr,
        16, 0, 0);
}

// ---------------- f32 -> bf16 convert (vectorized, grid-stride) ----------------
__global__ void cvt_bf16(const float* __restrict__ src, unsigned short* __restrict__ dst, long n8) {
    long i = blockIdx.x * (long)blockDim.x + threadIdx.x;
    long stride = (long)gridDim.x * blockDim.x;
    for (; i < n8; i += stride) {
        f32x4 a = *(const f32x4*)(src + i * 8);
        f32x4 b = *(const f32x4*)(src + i * 8 + 4);
        u16x8 o;
#pragma unroll
        for (int j = 0; j < 4; ++j) { o[j] = f2b(a[j]); o[4 + j] = f2b(b[j]); }
        *(u16x8*)(dst + i * 8) = o;
    }
}

// fused 5-way convert
__global__ void cvt5(const float* __restrict__ s0, const float* __restrict__ s1,
                     const float* __restrict__ s2, const float* __restrict__ s3,
                     const float* __restrict__ s4,
                     unsigned short* __restrict__ d0, unsigned short* __restrict__ d1,
                     unsigned short* __restrict__ d2, unsigned short* __restrict__ d3,
                     unsigned short* __restrict__ d4,
                     long n0, long n1) {
    const float* s; unsigned short* d; long n;
    switch (blockIdx.z) {
        case 0: s = s0; d = d0; n = n0; break;
        case 1: s = s1; d = d1; n = n1; break;
        case 2: s = s2; d = d2; n = n1; break;
        case 3: s = s3; d = d3; n = n1; break;
        default: s = s4; d = d4; n = n1; break;
    }
    long i = blockIdx.x * (long)blockDim.x + threadIdx.x;
    long stride = (long)gridDim.x * blockDim.x;
    for (; i < n; i += stride) {
        f32x4 a = *(const f32x4*)(s + i * 8);
        f32x4 b = *(const f32x4*)(s + i * 8 + 4);
        u16x8 o;
#pragma unroll
        for (int j = 0; j < 4; ++j) { o[j] = f2b(a[j]); o[4 + j] = f2b(b[j]); }
        *(u16x8*)(d + i * 8) = o;
    }
}

// ===== depth-2 pipelined GEMM: 128x256 tile, BK=32, 4 waves, 3 LDS buffers ===
// Per-wave output 64x128 (12 frag-reads -> 32 MFMA, density 2.67). One barrier
// per K-iter; counted vmcnt(6) keeps 6-12 loads in flight (T3/T4). Safety:
// interval t reads buf[t%3], stages tile t+2 into buf[(t+2)%3] (last read at
// t-1, sealed by barrier); vmcnt(6) before barrier -> tile t+1 resident.
// MODE 0: fused QKV epilogue (Q @Cout scaled, K @+8M, V transposed @+16M)
// MODE 2: f32 C = A.B^T + bias
template <int MODE>
__launch_bounds__(256)
__global__ void gemm_p(const unsigned short* __restrict__ A,
                       const unsigned short* __restrict__ Bw,
                       const float* __restrict__ b0, const float* __restrict__ b1,
                       const float* __restrict__ b2,
                       void* __restrict__ Cout, float rs) {
    __shared__ char LDS[73728];   // As: 3 x 8 KB @0; Bs: 3 x 16 KB @24576
    const int tid  = threadIdx.x;
    const int lane = tid & 63;
    const int w    = tid >> 6;
    const int wr   = w >> 1;      // 0..1: M half (64 rows)
    const int wcn  = w & 1;       // 0..1: N half (128 cols)

    const int wgid = blockIdx.y * gridDim.x + blockIdx.x;
    const int cpx  = (gridDim.x * gridDim.y) >> 3;
    const int swz  = (wgid & 7) * cpx + (wgid >> 3);
    const int m0  = (swz % gridDim.x) * 128;
    const int n0g = (swz / gridDim.x) * 256;

    const long rowB = (long)HDIM * 2;

    const char* Ab = (const char*)A  + (long)m0  * rowB;
    const char* Bb = (const char*)Bw + (long)n0g * rowB;

    // stage tile T (k in [T*32,T*32+32)): A 2 issues, B 4 issues
#define STG(T, bi) do {                                                          \
    _Pragma("unroll")                                                            \
    for (int i_ = 0; i_ < 2; ++i_) {                                             \
        int c = tid + i_ * 256; int row = c >> 2; int cb = (c & 3) * 16;         \
        gld_lds16(Ab + (long)row * rowB + (T) * 64 + cb,                         \
                  LDS + (bi) * 8192 + c * 16);                                   \
    }                                                                            \
    _Pragma("unroll")                                                            \
    for (int i_ = 0; i_ < 4; ++i_) {                                             \
        int c = tid + i_ * 256; int row = c >> 2; int cb = (c & 3) * 16;         \
        gld_lds16(Bb + (long)row * rowB + (T) * 64 + cb,                         \
                  LDS + 24576 + (bi) * 16384 + c * 16);                          \
    } } while (0)

    f32x4 acc[4][8] = {};
    const int NT = HDIM / 32;   // 64

    STG(0, 0);
    STG(1, 1);
    asm volatile("s_waitcnt vmcnt(6)" ::: "memory");   // tile 0 resident
    __builtin_amdgcn_s_barrier();

    int bi = 0;
    for (int t = 0; t < NT; ++t) {
        if (t + 2 < NT) {
            int nb = bi + 2; if (nb >= 3) nb -= 3;
            STG(t + 2, nb);
        }
        const char* Ar = LDS + bi * 8192;
        const char* Br = LDS + 24576 + bi * 16384;
        bf16x8 af[4], bfr[8];
#pragma unroll
        for (int f = 0; f < 4; ++f)
            af[f] = *(const bf16x8*)(Ar + (wr * 64 + f * 16 + (lane & 15)) * 64 + (lane >> 4) * 16);
#pragma unroll
        for (int f = 0; f < 8; ++f)
            bfr[f] = *(const bf16x8*)(Br + (wcn * 128 + f * 16 + (lane & 15)) * 64 + (lane >> 4) * 16);
        if (t + 2 < NT) asm volatile("s_waitcnt vmcnt(6)" ::: "memory");  // tile t+1 landed
        else            asm volatile("s_waitcnt vmcnt(0)" ::: "memory");
        __builtin_amdgcn_s_setprio(1);
#pragma unroll
        for (int mf = 0; mf < 4; ++mf)
#pragma unroll
            for (int nf = 0; nf < 8; ++nf)
                acc[mf][nf] = __builtin_amdgcn_mfma_f32_16x16x32_bf16(af[mf], bfr[nf], acc[mf][nf], 0, 0, 0);
        __builtin_amdgcn_s_setprio(0);
        __builtin_amdgcn_s_barrier();
        bi = (bi + 1 >= 3) ? 0 : bi + 1;
    }
#undef STG

    // ---- epilogue ----
    if (MODE == 0) {
        const int mat = n0g >> 11;                       // 0=Q 1=K 2=V
        const float* bb = (mat == 0) ? b0 : (mat == 1) ? b1 : b2;
        unsigned short* O = (unsigned short*)Cout + (long)mat * 8388608;
        if (mat < 2) {
            const float scale = (mat == 0) ? rs : 1.0f;
#pragma unroll
            for (int mf = 0; mf < 4; ++mf) {
#pragma unroll
                for (int nf = 0; nf < 8; ++nf) {
                    int nn = (n0g + wcn * 128 + nf * 16 + (lane & 15)) & 2047;
                    int nh = nn >> 7, hd = nn & 127;
                    float bv_ = bb[nn];
#pragma unroll
                    for (int j = 0; j < 4; ++j) {
                        int m = m0 + wr * 64 + mf * 16 + (lane >> 4) * 4 + j;
                        int b = m >> 11, s = m & 2047;
                        float v = (acc[mf][nf][j] + bv_) * scale;
                        O[((long)(b * NHEAD + nh) * SEQ + s) * HEADD + hd] = f2b(v);
                    }
                }
            }
        } else {
            // V: transpose through LDS (drained after K-loop), coalesced stores
            unsigned short* Tr = (unsigned short*)LDS;   // [256 n][136 m-stride]
            const int nn0 = n0g & 2047;
#pragma unroll
            for (int mf = 0; mf < 4; ++mf) {
#pragma unroll
                for (int nf = 0; nf < 8; ++nf) {
                    int nl = wcn * 128 + nf * 16 + (lane & 15);
                    float bv_ = bb[nn0 + nl];
#pragma unroll
                    for (int j = 0; j < 4; j += 2) {
                        int ml = wr * 64 + mf * 16 + (lane >> 4) * 4 + j;
                        unsigned int pk = f2b(acc[mf][nf][j] + bv_)
                                        | ((unsigned int)f2b(acc[mf][nf][j + 1] + bv_) << 16);
                        *(unsigned int*)((char*)Tr + nl * 272 + ml * 2) = pk;
                    }
                }
            }
            __syncthreads();
            // 256 rows (n), each 128 m-values = 256 B; one row per thread
            const int nl  = tid;
            const int hd  = nl & 127;
            const int nh  = (nn0 >> 7) + (nl >> 7);
            const int b = m0 >> 11, s0 = m0 & 2047;
            unsigned short* dst = O + ((long)(b * NHEAD + nh) * HEADD + hd) * SEQ + s0;
            const unsigned short* srcl = Tr + nl * 136;
#pragma unroll
            for (int k = 0; k < 16; ++k)
                *(u16x8*)(dst + k * 8) = *(const u16x8*)(srcl + k * 8);
        }
    } else {
        float* O = (float*)Cout;
#pragma unroll
        for (int mf = 0; mf < 4; ++mf) {
#pragma unroll
            for (int nf = 0; nf < 8; ++nf) {
                int n = n0g + wcn * 128 + nf * 16 + (lane & 15);
                float bv = b0[n];
#pragma unroll
                for (int j = 0; j < 4; ++j) {
                    int m = m0 + wr * 64 + mf * 16 + (lane >> 4) * 4 + j;
                    O[(long)m * HDIM + n] = acc[mf][nf][j] + bv;
                }
            }
        }
    }
}

// ---------------- causal flash attention (log2-domain softmax) ----------------
// 512 threads = 8 waves = 4 pairs x 32 q-rows; waves of a pair split the 64-kv
// tile. Q pre-scaled by (1/sqrt(HD))*log2(e) -> S in log2 units; exp2f used.
#define MASKV (-3.0e38f)

__device__ __forceinline__ void attn_step32s(
    const unsigned short* Ksb, const unsigned short* Vsb,
    const bf16x8 (&qf)[8], f32x16 (&acc)[4], float& mrun, float& lrun,
    int lane, int p, int q0w, int kvt, bool diag)
{
    const int ql = lane & 31;
    const int hi = lane >> 5;

    f32x16 sv = {};
    {
        const int row = p * 32 + ql;
        const int sw  = (row & 7) << 4;
        __builtin_amdgcn_s_setprio(1);
#pragma unroll
        for (int kc = 0; kc < 8; ++kc) {
            int off = (row * 256 + ((kc * 32 + hi * 16) ^ sw)) >> 1;
            bf16x8 kf = *(const bf16x8*)&Ksb[off];
            sv = __builtin_amdgcn_mfma_f32_32x32x16_bf16(kf, qf[kc], sv, 0, 0, 0);
        }
        __builtin_amdgcn_s_setprio(0);
    }

    if (diag) {
        const int qg = q0w + ql;
#pragma unroll
        for (int r = 0; r < 16; ++r) {
            int kv = kvt * 64 + p * 32 + (r & 3) + 8 * (r >> 2) + 4 * hi;
            if (kv > qg) sv[r] = MASKV;
        }
    }

    float tmax = sv[0];
#pragma unroll
    for (int r = 1; r < 16; ++r) tmax = fmaxf(tmax, sv[r]);
    tmax = fmaxf(tmax, __shfl_xor(tmax, 32));

    float mnew = mrun, sc = 1.0f;
    if (__any(tmax > mrun + 11.5f)) {   // defer-max (log2 units ~= 8 nats)
        mnew = fmaxf(mrun, tmax);
        sc = exp2f(mrun - mnew);
#pragma unroll
        for (int db = 0; db < 4; ++db) acc[db] *= sc;
    }
    float rsum = 0.f;
#pragma unroll
    for (int r = 0; r < 16; ++r) {
        float pv = exp2f(sv[r] - mnew);
        sv[r] = pv;
        rsum += pv;
    }
    rsum += __shfl_xor(rsum, 32);
    lrun = lrun * sc + rsum;
    mrun = mnew;

    // T12: in-register P assembly
    bf16x8 pf[2];
#pragma unroll
    for (int kc2 = 0; kc2 < 2; ++kc2) {
        unsigned int w01 = f2b(sv[8 * kc2 + 0]) | ((unsigned int)f2b(sv[8 * kc2 + 1]) << 16);
        unsigned int w23 = f2b(sv[8 * kc2 + 2]) | ((unsigned int)f2b(sv[8 * kc2 + 3]) << 16);
        unsigned int w45 = f2b(sv[8 * kc2 + 4]) | ((unsigned int)f2b(sv[8 * kc2 + 5]) << 16);
        unsigned int w67 = f2b(sv[8 * kc2 + 6]) | ((unsigned int)f2b(sv[8 * kc2 + 7]) << 16);
        asm volatile("v_permlane32_swap_b32 %0, %1" : "+v"(w01), "+v"(w45));
        asm volatile("v_permlane32_swap_b32 %0, %1" : "+v"(w23), "+v"(w67));
        union { unsigned int u[4]; bf16x8 v; } pk;
        pk.u[0] = w01; pk.u[1] = w23; pk.u[2] = w45; pk.u[3] = w67;
        pf[kc2] = pk.v;
    }

    __builtin_amdgcn_s_setprio(1);
#pragma unroll
    for (int db = 0; db < 4; ++db) {
        const int row = db * 32 + ql;
        const int sw  = (row & 7) << 4;
#pragma unroll
        for (int kc2 = 0; kc2 < 2; ++kc2) {
            int off = (row * 128 + ((p * 64 + kc2 * 32 + hi * 16) ^ sw)) >> 1;
            bf16x8 vf = *(const bf16x8*)&Vsb[off];
            acc[db] = __builtin_amdgcn_mfma_f32_32x32x16_bf16(vf, pf[kc2], acc[db], 0, 0, 0);
        }
    }
    __builtin_amdgcn_s_setprio(0);
}

__device__ __forceinline__ void attn_merge_store(
    f32x16 (&acc)[4], float mrun, float lrun,
    float (*Mx)[32], float (*Lx)[32], f32x16 (*Ob)[64],
    unsigned short* __restrict__ Out, long rowbase, int lane, int wp, int p)
{
    const int ql = lane & 31, hi = lane >> 5;
    Mx[wp * 2 + p][ql] = mrun;
    Lx[wp * 2 + p][ql] = lrun;
    __syncthreads();
    const float mo = Mx[wp * 2 + 1 - p][ql];
    const float lo = Lx[wp * 2 + 1 - p][ql];
    const float M  = fmaxf(mrun, mo);
    const float a  = exp2f(mrun - M);
    const float L  = lrun * a + lo * exp2f(mo - M);
#pragma unroll
    for (int db = 0; db < 4; ++db) acc[db] *= a;
#pragma unroll
    for (int db = 0; db < 4; ++db) {
        if (p == 1) Ob[wp][lane] = acc[db];
        __syncthreads();
        if (p == 0) acc[db] += Ob[wp][lane];
        __syncthreads();
    }
    if (p == 0) {
        const float inv = 1.0f / L;
        const long base = rowbase + (long)ql * HDIM;
#pragma unroll
        for (int db = 0; db < 4; ++db)
#pragma unroll
            for (int mm = 0; mm < 4; ++mm) {
                int d0 = db * 32 + 8 * mm + 4 * hi;
                unsigned int w0 = f2b(acc[db][4 * mm + 0] * inv) | ((unsigned int)f2b(acc[db][4 * mm + 1] * inv) << 16);
                unsigned int w1 = f2b(acc[db][4 * mm + 2] * inv) | ((unsigned int)f2b(acc[db][4 * mm + 3] * inv) << 16);
                *(unsigned long long*)(Out + base + d0) =
                    (unsigned long long)w0 | ((unsigned long long)w1 << 32);
            }
    }
}

__launch_bounds__(512, 1)
__global__ void attn_fwd(const unsigned short* __restrict__ Q,
                         const unsigned short* __restrict__ K,
                         const unsigned short* __restrict__ Vt,
                         unsigned short* __restrict__ Out) {
    __shared__ unsigned short Ks[2][64 * 128];
    __shared__ unsigned short Vs[2][128 * 64];
    __shared__ float Mx[8][32];
    __shared__ float Lx[8][32];
    __shared__ f32x16 Ob[4][64];

    const int tid  = threadIdx.x;
    const int lane = tid & 63;
    const int w    = tid >> 6;
    const int wp   = w & 3;
    const int p    = w >> 2;

    const int id  = blockIdx.x;
    const int xcd = id & 7;
    const int j   = id >> 3;
    const int bh  = xcd * 4 + (j >> 3);
    const int x   = j & 7;
    const int hiT = 15 - x;
    const int loT = x;
    const int nA  = 2 * hiT + 2;
    const int nB  = 2 * loT + 2;
    const int q0A = hiT * 128 + wp * 32;
    const int q0B = loT * 128 + wp * 32;

    const char* Kbase = (const char*)(K  + (long)bh * SEQ * HEADD);
    const char* Vbase = (const char*)(Vt + (long)bh * HEADD * SEQ);

#define STAGE(kvt, bb) do {                                                             \
    _Pragma("unroll")                                                                   \
    for (int i = 0; i < 2; ++i) {                                                       \
        int c = tid + i * 512;                                                          \
        int rowk = c >> 4;                                                              \
        int cbk  = ((c & 15) * 16) ^ ((rowk & 7) << 4);                                 \
        gld_lds16(Kbase + (long)((kvt) * 64 + rowk) * 256 + cbk, (char*)Ks[bb] + c * 16);\
        int rowv = c >> 3;                                                              \
        int cbv  = ((c & 7) * 16) ^ ((rowv & 7) << 4);                                  \
        gld_lds16(Vbase + (long)rowv * (SEQ * 2) + (kvt) * 128 + cbv, (char*)Vs[bb] + c * 16); \
    } } while (0)

    const int b = bh >> 4, nh = bh & 15;
    int buf = 0;

    STAGE(0, 0);
    __syncthreads();

    {
        bf16x8 qf[8];
#pragma unroll
        for (int kc = 0; kc < 8; ++kc)
            qf[kc] = *(const bf16x8*)&Q[((long)bh * SEQ + q0A + (lane & 31)) * HEADD + kc * 16 + (lane >> 5) * 8];

        f32x16 acc[4] = {};
        float mrun = -1e30f, lrun = 0.f;
        for (int s = 0; s < nA; ++s) {
            if (s + 1 < nA) STAGE(s + 1, buf ^ 1);
            else            STAGE(0, buf ^ 1);
            attn_step32s(Ks[buf], Vs[buf], qf, acc, mrun, lrun,
                         lane, p, q0A, s, s * 64 + 63 > q0A);
            __syncthreads();
            buf ^= 1;
        }
        attn_merge_store(acc, mrun, lrun, Mx, Lx, Ob, Out,
                         ((long)(b * SEQ) + q0A) * HDIM + nh * HEADD, lane, wp, p);
    }

    {
        bf16x8 qf[8];
#pragma unroll
        for (int kc = 0; kc < 8; ++kc)
            qf[kc] = *(const bf16x8*)&Q[((long)bh * SEQ + q0B + (lane & 31)) * HEADD + kc * 16 + (lane >> 5) * 8];

        f32x16 acc[4] = {};
        float mrun = -1e30f, lrun = 0.f;
        for (int s = 0; s < nB; ++s) {
            if (s + 1 < nB) STAGE(s + 1, buf ^ 1);
            attn_step32s(Ks[buf], Vs[buf], qf, acc, mrun, lrun,
                         lane, p, q0B, s, s * 64 + 63 > q0B);
            __syncthreads();
            buf ^= 1;
        }
        attn_merge_store(acc, mrun, lrun, Mx, Lx, Ob, Out,
                         ((long)(b * SEQ) + q0B) * HDIM + nh * HEADD, lane, wp, p);
    }
#undef STAGE
}

// ---------------- launcher ----------------
extern "C" void kernel_launch(void* const* d_in, const int* in_sizes, int n_in,
                              void* d_out, int out_size, void* d_ws, size_t ws_size,
                              hipStream_t stream) {
    const float* hs = (const float*)d_in[0];
    const float* Wq = (const float*)d_in[2];
    const float* bq = (const float*)d_in[3];
    const float* Wk = (const float*)d_in[4];
    const float* bk = (const float*)d_in[5];
    const float* Wv = (const float*)d_in[6];
    const float* bv = (const float*)d_in[7];
    const float* Wo = (const float*)d_in[8];
    const float* bo = (const float*)d_in[9];
    float* out = (float*)d_out;

    char* ws = (char*)d_ws;
    const long MB = 1024L * 1024L;
    // 1/sqrt(128) * log2(e): S computed in log2 domain for exp2-softmax
    const float rs = 0.08838834764831845f * 1.4426950408889634f;

    if (ws_size >= 96 * MB) {
        unsigned short* hsb  = (unsigned short*)ws;               // 16 MB (reused as attn out)
        unsigned short* wqkv = (unsigned short*)(ws + 16 * MB);   // 24 MB: Wq|Wk|Wv [6144][2048]
        unsigned short* wob  = (unsigned short*)(ws + 40 * MB);   //  8 MB
        unsigned short* qb   = (unsigned short*)(ws + 48 * MB);   // kb=+8M, vtb=+16M elems
        unsigned short* kb   = (unsigned short*)(ws + 64 * MB);
        unsigned short* vtb  = (unsigned short*)(ws + 80 * MB);
        unsigned short* aob  = hsb;
        unsigned short* wqb  = wqkv;
        unsigned short* wkb  = wqkv + 2048L * 2048;
        unsigned short* wvb  = wqkv + 2L * 2048 * 2048;

        cvt5<<<dim3(1024, 1, 5), 256, 0, stream>>>(
            hs, Wq, Wk, Wv, Wo,
            hsb, wqb, wkb, wvb, wob,
            (long)MTOT * HDIM / 8, (long)HDIM * HDIM / 8);
        gemm_p<0><<<dim3(32, 24), 256, 0, stream>>>(hsb, wqkv, bq, bk, bv, qb, rs);
        attn_fwd<<<256, 512, 0, stream>>>(qb, kb, vtb, aob);
        gemm_p<2><<<dim3(32, 8), 256, 0, stream>>>(aob, wob, bo, bo, bo, out, 1.0f);
    } else {
        // tighter layout: 88 MB; convert Wo into wqkv space after QKV GEMM
        unsigned short* hsb  = (unsigned short*)ws;               // 16 MB
        unsigned short* wqkv = (unsigned short*)(ws + 16 * MB);   // 24 MB
        unsigned short* qb   = (unsigned short*)(ws + 40 * MB);
        unsigned short* kb   = (unsigned short*)(ws + 56 * MB);
        unsigned short* vtb  = (unsigned short*)(ws + 72 * MB);
        unsigned short* aob  = hsb;

        cvt_bf16<<<2048, 256, 0, stream>>>(hs, hsb, (long)MTOT * HDIM / 8);
        cvt_bf16<<<2048, 256, 0, stream>>>(Wq, wqkv, (long)HDIM * HDIM / 8);
        cvt_bf16<<<2048, 256, 0, stream>>>(Wk, wqkv + 2048L * 2048, (long)HDIM * HDIM / 8);
        cvt_bf16<<<2048, 256, 0, stream>>>(Wv, wqkv + 2L * 2048 * 2048, (long)HDIM * HDIM / 8);
        gemm_p<0><<<dim3(32, 24), 256, 0, stream>>>(hsb, wqkv, bq, bk, bv, qb, rs);
        attn_fwd<<<256, 512, 0, stream>>>(qb, kb, vtb, aob);
        cvt_bf16<<<2048, 256, 0, stream>>>(Wo, wqkv, (long)HDIM * HDIM / 8);
        gemm_p<2><<<dim3(32, 8), 256, 0, stream>>>(aob, wqkv, bo, bo, bo, out, 1.0f);
    }
}

// Round 15
// 276.915 us; speedup vs baseline: 1.0273x; 1.0273x over previous
//
#include <hip/hip_runtime.h>
#include <hip/hip_bf16.h>

#define SEQ   2048
#define HDIM  2048
#define NHEAD 16
#define HEADD 128
#define BATCH 2
#define MTOT  (BATCH*SEQ)   // 4096
#define BH    (BATCH*NHEAD) // 32

typedef __attribute__((ext_vector_type(8))) __bf16 bf16x8;
typedef __attribute__((ext_vector_type(4))) float f32x4;
typedef __attribute__((ext_vector_type(16))) float f32x16;
typedef __attribute__((ext_vector_type(8))) unsigned short u16x8;

__device__ __forceinline__ unsigned short f2b(float f) {
    __bf16 h = (__bf16)f;
    return __builtin_bit_cast(unsigned short, h);
}

__device__ __forceinline__ void gld_lds16(const void* gptr, void* ldsptr) {
    __builtin_amdgcn_global_load_lds(
        (const __attribute__((address_space(1))) unsigned int*)gptr,
        (__attribute__((address_space(3))) unsigned int*)ldsptr,
        16, 0, 0);
}

// ---------------- f32 -> bf16 convert (vectorized, grid-stride) ----------------
__global__ void cvt_bf16(const float* __restrict__ src, unsigned short* __restrict__ dst, long n8) {
    long i = blockIdx.x * (long)blockDim.x + threadIdx.x;
    long stride = (long)gridDim.x * blockDim.x;
    for (; i < n8; i += stride) {
        f32x4 a = *(const f32x4*)(src + i * 8);
        f32x4 b = *(const f32x4*)(src + i * 8 + 4);
        u16x8 o;
#pragma unroll
        for (int j = 0; j < 4; ++j) { o[j] = f2b(a[j]); o[4 + j] = f2b(b[j]); }
        *(u16x8*)(dst + i * 8) = o;
    }
}

// fused 5-way convert
__global__ void cvt5(const float* __restrict__ s0, const float* __restrict__ s1,
                     const float* __restrict__ s2, const float* __restrict__ s3,
                     const float* __restrict__ s4,
                     unsigned short* __restrict__ d0, unsigned short* __restrict__ d1,
                     unsigned short* __restrict__ d2, unsigned short* __restrict__ d3,
                     unsigned short* __restrict__ d4,
                     long n0, long n1) {
    const float* s; unsigned short* d; long n;
    switch (blockIdx.z) {
        case 0: s = s0; d = d0; n = n0; break;
        case 1: s = s1; d = d1; n = n1; break;
        case 2: s = s2; d = d2; n = n1; break;
        case 3: s = s3; d = d3; n = n1; break;
        default: s = s4; d = d4; n = n1; break;
    }
    long i = blockIdx.x * (long)blockDim.x + threadIdx.x;
    long stride = (long)gridDim.x * blockDim.x;
    for (; i < n; i += stride) {
        f32x4 a = *(const f32x4*)(s + i * 8);
        f32x4 b = *(const f32x4*)(s + i * 8 + 4);
        u16x8 o;
#pragma unroll
        for (int j = 0; j < 4; ++j) { o[j] = f2b(a[j]); o[4 + j] = f2b(b[j]); }
        *(u16x8*)(d + i * 8) = o;
    }
}

// ======= depth-2 pipelined GEMM: 128x128 tile, BK=32, 3 LDS buffers =========
// r13 schedule (1 barrier/iter, counted vmcnt(4)) + T2 LDS swizzle:
// each 8KB tile stored as 64 LDS rows x 128B (2 m-rows/LDS-row) with
// ucol = col ^ ((r&7)<<4). Staged via inverse-permuted GLOBAL source
// (LDS dest stays linear, rule #21); reads apply the same XOR.
// 16-lane fragment reads then hit banks exactly 2-way (free, m136).
// MODE 0: fused QKV epilogue (Q @Cout scaled, K @+8M, V transposed @+16M)
// MODE 2: f32 C = A.B^T + bias
template <int MODE>
__launch_bounds__(256)
__global__ void gemm_p(const unsigned short* __restrict__ A,
                       const unsigned short* __restrict__ Bw,
                       const float* __restrict__ b0, const float* __restrict__ b1,
                       const float* __restrict__ b2,
                       void* __restrict__ Cout, float rs) {
    __shared__ char LDS[49152];   // As: 3 x 8 KB @0; Bs: 3 x 8 KB @24576
    const int tid  = threadIdx.x;
    const int lane = tid & 63;
    const int w    = tid >> 6;

    const int wgid = blockIdx.y * gridDim.x + blockIdx.x;
    const int cpx  = (gridDim.x * gridDim.y) >> 3;
    const int swz  = (wgid & 7) * cpx + (wgid >> 3);
    const int m0  = (swz % gridDim.x) * 128;
    const int n0g = (swz / gridDim.x) * 128;

    const int wr = (w >> 1) * 64, wc = (w & 1) * 64;
    const long rowB = (long)HDIM * 2;

    const char* Ab = (const char*)A  + (long)m0  * rowB;
    const char* Bb = (const char*)Bw + (long)n0g * rowB;

    // stage tile T (k in [T*32,T*32+32)) into buffer bi (4 issues/thread).
    // chunk c (0..511) -> LDS row r=c>>3, slot c&7; source column is the
    // swizzle-inverse so that a swizzled READ returns the right element.
#define STG(T, bi) do {                                                          \
    _Pragma("unroll")                                                            \
    for (int i_ = 0; i_ < 2; ++i_) {                                             \
        int c = tid + i_ * 256;                                                  \
        int r_ = c >> 3;                                                         \
        int ucol = ((c & 7) * 16) ^ ((r_ & 7) << 4);                             \
        long srcoff = (long)(2 * r_ + (ucol >> 6)) * rowB + (T) * 64 + (ucol & 63); \
        gld_lds16(Ab + srcoff, LDS + (bi) * 8192 + c * 16);                      \
        gld_lds16(Bb + srcoff, LDS + 24576 + (bi) * 8192 + c * 16);              \
    } } while (0)

    // swizzled fragment address for m-row mm, k-slot s (16B units)
#define FRADDR(mm, s) (((mm) >> 1) * 128 + (((((mm) & 1) << 6) + ((s) << 4)) ^ ((((mm) >> 1) & 7) << 4)))

    f32x4 acc[4][4] = {};
    const int NT = HDIM / 32;   // 64

    STG(0, 0);
    STG(1, 1);
    asm volatile("s_waitcnt vmcnt(4)" ::: "memory");   // tile 0 resident
    __builtin_amdgcn_s_barrier();

    int bi = 0;
    for (int t = 0; t < NT; ++t) {
        if (t + 2 < NT) {
            int nb = bi + 2; if (nb >= 3) nb -= 3;
            STG(t + 2, nb);
        }
        const char* Ar = LDS + bi * 8192;
        const char* Br = LDS + 24576 + bi * 8192;
        const int s = lane >> 4;
        bf16x8 af[4], bfr[4];
#pragma unroll
        for (int f = 0; f < 4; ++f) {
            int mma = wr + f * 16 + (lane & 15);
            int mmb = wc + f * 16 + (lane & 15);
            af[f]  = *(const bf16x8*)(Ar + FRADDR(mma, s));
            bfr[f] = *(const bf16x8*)(Br + FRADDR(mmb, s));
        }
        if (t + 2 < NT) asm volatile("s_waitcnt vmcnt(4)" ::: "memory");  // tile t+1 landed
        else            asm volatile("s_waitcnt vmcnt(0)" ::: "memory");
        __builtin_amdgcn_s_setprio(1);
#pragma unroll
        for (int mf = 0; mf < 4; ++mf)
#pragma unroll
            for (int nf = 0; nf < 4; ++nf)
                acc[mf][nf] = __builtin_amdgcn_mfma_f32_16x16x32_bf16(af[mf], bfr[nf], acc[mf][nf], 0, 0, 0);
        __builtin_amdgcn_s_setprio(0);
        __builtin_amdgcn_s_barrier();
        bi = (bi + 1 >= 3) ? 0 : bi + 1;
    }
#undef STG
#undef FRADDR

    // ---- epilogue ----
    if (MODE == 0) {
        const int mat = n0g >> 11;                       // 0=Q 1=K 2=V
        const float* bb = (mat == 0) ? b0 : (mat == 1) ? b1 : b2;
        unsigned short* O = (unsigned short*)Cout + (long)mat * 8388608;
        if (mat < 2) {
            const float scale = (mat == 0) ? rs : 1.0f;
#pragma unroll
            for (int mf = 0; mf < 4; ++mf) {
#pragma unroll
                for (int nf = 0; nf < 4; ++nf) {
                    int nn = (n0g + wc + nf * 16 + (lane & 15)) & 2047;
                    int nh = nn >> 7, hd = nn & 127;
                    float bv_ = bb[nn];
#pragma unroll
                    for (int j = 0; j < 4; ++j) {
                        int m = m0 + wr + mf * 16 + (lane >> 4) * 4 + j;
                        int b = m >> 11, s2 = m & 2047;
                        float v = (acc[mf][nf][j] + bv_) * scale;
                        O[((long)(b * NHEAD + nh) * SEQ + s2) * HEADD + hd] = f2b(v);
                    }
                }
            }
        } else {
            // V: transpose through LDS (drained after K-loop), coalesced stores
            unsigned short* Tr = (unsigned short*)LDS;   // [128 n][136 m-stride]
            const int nn0 = n0g & 2047;
#pragma unroll
            for (int mf = 0; mf < 4; ++mf) {
#pragma unroll
                for (int nf = 0; nf < 4; ++nf) {
                    int nl = wc + nf * 16 + (lane & 15);
                    float bv_ = bb[nn0 + nl];
#pragma unroll
                    for (int j = 0; j < 4; j += 2) {
                        int ml = wr + mf * 16 + (lane >> 4) * 4 + j;
                        unsigned int pk = f2b(acc[mf][nf][j] + bv_)
                                        | ((unsigned int)f2b(acc[mf][nf][j + 1] + bv_) << 16);
                        *(unsigned int*)((char*)Tr + nl * 272 + ml * 2) = pk;
                    }
                }
            }
            __syncthreads();
            const int nh  = nn0 >> 7;
            const int row = tid >> 1, half = tid & 1;
            const int b = m0 >> 11, s0 = m0 & 2047;
            unsigned short* dst = O + ((long)(b * NHEAD + nh) * HEADD + row) * SEQ + s0 + half * 64;
            const unsigned short* srcl = Tr + row * 136 + half * 64;
#pragma unroll
            for (int k = 0; k < 8; ++k)
                *(u16x8*)(dst + k * 8) = *(const u16x8*)(srcl + k * 8);
        }
    } else {
        float* O = (float*)Cout;
#pragma unroll
        for (int mf = 0; mf < 4; ++mf) {
#pragma unroll
            for (int nf = 0; nf < 4; ++nf) {
                int n = n0g + wc + nf * 16 + (lane & 15);
                float bv = b0[n];
#pragma unroll
                for (int j = 0; j < 4; ++j) {
                    int m = m0 + wr + mf * 16 + (lane >> 4) * 4 + j;
                    O[(long)m * HDIM + n] = acc[mf][nf][j] + bv;
                }
            }
        }
    }
}

// ---------------- causal flash attention (log2-domain softmax) ----------------
// 512 threads = 8 waves = 4 pairs x 32 q-rows; waves of a pair split the 64-kv
// tile. Q pre-scaled by (1/sqrt(HD))*log2(e) -> S in log2 units; exp2f used.
#define MASKV (-3.0e38f)

__device__ __forceinline__ void attn_step32s(
    const unsigned short* Ksb, const unsigned short* Vsb,
    const bf16x8 (&qf)[8], f32x16 (&acc)[4], float& mrun, float& lrun,
    int lane, int p, int q0w, int kvt, bool diag)
{
    const int ql = lane & 31;
    const int hi = lane >> 5;

    f32x16 sv = {};
    {
        const int row = p * 32 + ql;
        const int sw  = (row & 7) << 4;
        __builtin_amdgcn_s_setprio(1);
#pragma unroll
        for (int kc = 0; kc < 8; ++kc) {
            int off = (row * 256 + ((kc * 32 + hi * 16) ^ sw)) >> 1;
            bf16x8 kf = *(const bf16x8*)&Ksb[off];
            sv = __builtin_amdgcn_mfma_f32_32x32x16_bf16(kf, qf[kc], sv, 0, 0, 0);
        }
        __builtin_amdgcn_s_setprio(0);
    }

    if (diag) {
        const int qg = q0w + ql;
#pragma unroll
        for (int r = 0; r < 16; ++r) {
            int kv = kvt * 64 + p * 32 + (r & 3) + 8 * (r >> 2) + 4 * hi;
            if (kv > qg) sv[r] = MASKV;
        }
    }

    float tmax = sv[0];
#pragma unroll
    for (int r = 1; r < 16; ++r) tmax = fmaxf(tmax, sv[r]);
    tmax = fmaxf(tmax, __shfl_xor(tmax, 32));

    float mnew = mrun, sc = 1.0f;
    if (__any(tmax > mrun + 11.5f)) {   // defer-max (log2 units ~= 8 nats)
        mnew = fmaxf(mrun, tmax);
        sc = exp2f(mrun - mnew);
#pragma unroll
        for (int db = 0; db < 4; ++db) acc[db] *= sc;
    }
    float rsum = 0.f;
#pragma unroll
    for (int r = 0; r < 16; ++r) {
        float pv = exp2f(sv[r] - mnew);
        sv[r] = pv;
        rsum += pv;
    }
    rsum += __shfl_xor(rsum, 32);
    lrun = lrun * sc + rsum;
    mrun = mnew;

    // T12: in-register P assembly
    bf16x8 pf[2];
#pragma unroll
    for (int kc2 = 0; kc2 < 2; ++kc2) {
        unsigned int w01 = f2b(sv[8 * kc2 + 0]) | ((unsigned int)f2b(sv[8 * kc2 + 1]) << 16);
        unsigned int w23 = f2b(sv[8 * kc2 + 2]) | ((unsigned int)f2b(sv[8 * kc2 + 3]) << 16);
        unsigned int w45 = f2b(sv[8 * kc2 + 4]) | ((unsigned int)f2b(sv[8 * kc2 + 5]) << 16);
        unsigned int w67 = f2b(sv[8 * kc2 + 6]) | ((unsigned int)f2b(sv[8 * kc2 + 7]) << 16);
        asm volatile("v_permlane32_swap_b32 %0, %1" : "+v"(w01), "+v"(w45));
        asm volatile("v_permlane32_swap_b32 %0, %1" : "+v"(w23), "+v"(w67));
        union { unsigned int u[4]; bf16x8 v; } pk;
        pk.u[0] = w01; pk.u[1] = w23; pk.u[2] = w45; pk.u[3] = w67;
        pf[kc2] = pk.v;
    }

    __builtin_amdgcn_s_setprio(1);
#pragma unroll
    for (int db = 0; db < 4; ++db) {
        const int row = db * 32 + ql;
        const int sw  = (row & 7) << 4;
#pragma unroll
        for (int kc2 = 0; kc2 < 2; ++kc2) {
            int off = (row * 128 + ((p * 64 + kc2 * 32 + hi * 16) ^ sw)) >> 1;
            bf16x8 vf = *(const bf16x8*)&Vsb[off];
            acc[db] = __builtin_amdgcn_mfma_f32_32x32x16_bf16(vf, pf[kc2], acc[db], 0, 0, 0);
        }
    }
    __builtin_amdgcn_s_setprio(0);
}

__device__ __forceinline__ void attn_merge_store(
    f32x16 (&acc)[4], float mrun, float lrun,
    float (*Mx)[32], float (*Lx)[32], f32x16 (*Ob)[64],
    unsigned short* __restrict__ Out, long rowbase, int lane, int wp, int p)
{
    const int ql = lane & 31, hi = lane >> 5;
    Mx[wp * 2 + p][ql] = mrun;
    Lx[wp * 2 + p][ql] = lrun;
    __syncthreads();
    const float mo = Mx[wp * 2 + 1 - p][ql];
    const float lo = Lx[wp * 2 + 1 - p][ql];
    const float M  = fmaxf(mrun, mo);
    const float a  = exp2f(mrun - M);
    const float L  = lrun * a + lo * exp2f(mo - M);
#pragma unroll
    for (int db = 0; db < 4; ++db) acc[db] *= a;
#pragma unroll
    for (int db = 0; db < 4; ++db) {
        if (p == 1) Ob[wp][lane] = acc[db];
        __syncthreads();
        if (p == 0) acc[db] += Ob[wp][lane];
        __syncthreads();
    }
    if (p == 0) {
        const float inv = 1.0f / L;
        const long base = rowbase + (long)ql * HDIM;
#pragma unroll
        for (int db = 0; db < 4; ++db)
#pragma unroll
            for (int mm = 0; mm < 4; ++mm) {
                int d0 = db * 32 + 8 * mm + 4 * hi;
                unsigned int w0 = f2b(acc[db][4 * mm + 0] * inv) | ((unsigned int)f2b(acc[db][4 * mm + 1] * inv) << 16);
                unsigned int w1 = f2b(acc[db][4 * mm + 2] * inv) | ((unsigned int)f2b(acc[db][4 * mm + 3] * inv) << 16);
                *(unsigned long long*)(Out + base + d0) =
                    (unsigned long long)w0 | ((unsigned long long)w1 << 32);
            }
    }
}

__launch_bounds__(512, 1)
__global__ void attn_fwd(const unsigned short* __restrict__ Q,
                         const unsigned short* __restrict__ K,
                         const unsigned short* __restrict__ Vt,
                         unsigned short* __restrict__ Out) {
    __shared__ unsigned short Ks[2][64 * 128];
    __shared__ unsigned short Vs[2][128 * 64];
    __shared__ float Mx[8][32];
    __shared__ float Lx[8][32];
    __shared__ f32x16 Ob[4][64];

    const int tid  = threadIdx.x;
    const int lane = tid & 63;
    const int w    = tid >> 6;
    const int wp   = w & 3;
    const int p    = w >> 2;

    const int id  = blockIdx.x;
    const int xcd = id & 7;
    const int j   = id >> 3;
    const int bh  = xcd * 4 + (j >> 3);
    const int x   = j & 7;
    const int hiT = 15 - x;
    const int loT = x;
    const int nA  = 2 * hiT + 2;
    const int nB  = 2 * loT + 2;
    const int q0A = hiT * 128 + wp * 32;
    const int q0B = loT * 128 + wp * 32;

    const char* Kbase = (const char*)(K  + (long)bh * SEQ * HEADD);
    const char* Vbase = (const char*)(Vt + (long)bh * HEADD * SEQ);

#define STAGE(kvt, bb) do {                                                             \
    _Pragma("unroll")                                                                   \
    for (int i = 0; i < 2; ++i) {                                                       \
        int c = tid + i * 512;                                                          \
        int rowk = c >> 4;                                                              \
        int cbk  = ((c & 15) * 16) ^ ((rowk & 7) << 4);                                 \
        gld_lds16(Kbase + (long)((kvt) * 64 + rowk) * 256 + cbk, (char*)Ks[bb] + c * 16);\
        int rowv = c >> 3;                                                              \
        int cbv  = ((c & 7) * 16) ^ ((rowv & 7) << 4);                                  \
        gld_lds16(Vbase + (long)rowv * (SEQ * 2) + (kvt) * 128 + cbv, (char*)Vs[bb] + c * 16); \
    } } while (0)

    const int b = bh >> 4, nh = bh & 15;
    int buf = 0;

    STAGE(0, 0);
    __syncthreads();

    {
        bf16x8 qf[8];
#pragma unroll
        for (int kc = 0; kc < 8; ++kc)
            qf[kc] = *(const bf16x8*)&Q[((long)bh * SEQ + q0A + (lane & 31)) * HEADD + kc * 16 + (lane >> 5) * 8];

        f32x16 acc[4] = {};
        float mrun = -1e30f, lrun = 0.f;
        for (int s = 0; s < nA; ++s) {
            if (s + 1 < nA) STAGE(s + 1, buf ^ 1);
            else            STAGE(0, buf ^ 1);
            attn_step32s(Ks[buf], Vs[buf], qf, acc, mrun, lrun,
                         lane, p, q0A, s, s * 64 + 63 > q0A);
            __syncthreads();
            buf ^= 1;
        }
        attn_merge_store(acc, mrun, lrun, Mx, Lx, Ob, Out,
                         ((long)(b * SEQ) + q0A) * HDIM + nh * HEADD, lane, wp, p);
    }

    {
        bf16x8 qf[8];
#pragma unroll
        for (int kc = 0; kc < 8; ++kc)
            qf[kc] = *(const bf16x8*)&Q[((long)bh * SEQ + q0B + (lane & 31)) * HEADD + kc * 16 + (lane >> 5) * 8];

        f32x16 acc[4] = {};
        float mrun = -1e30f, lrun = 0.f;
        for (int s = 0; s < nB; ++s) {
            if (s + 1 < nB) STAGE(s + 1, buf ^ 1);
            attn_step32s(Ks[buf], Vs[buf], qf, acc, mrun, lrun,
                         lane, p, q0B, s, s * 64 + 63 > q0B);
            __syncthreads();
            buf ^= 1;
        }
        attn_merge_store(acc, mrun, lrun, Mx, Lx, Ob, Out,
                         ((long)(b * SEQ) + q0B) * HDIM + nh * HEADD, lane, wp, p);
    }
#undef STAGE
}

// ---------------- launcher ----------------
extern "C" void kernel_launch(void* const* d_in, const int* in_sizes, int n_in,
                              void* d_out, int out_size, void* d_ws, size_t ws_size,
                              hipStream_t stream) {
    const float* hs = (const float*)d_in[0];
    const float* Wq = (const float*)d_in[2];
    const float* bq = (const float*)d_in[3];
    const float* Wk = (const float*)d_in[4];
    const float* bk = (const float*)d_in[5];
    const float* Wv = (const float*)d_in[6];
    const float* bv = (const float*)d_in[7];
    const float* Wo = (const float*)d_in[8];
    const float* bo = (const float*)d_in[9];
    float* out = (float*)d_out;

    char* ws = (char*)d_ws;
    const long MB = 1024L * 1024L;
    // 1/sqrt(128) * log2(e): S computed in log2 domain for exp2-softmax
    const float rs = 0.08838834764831845f * 1.4426950408889634f;

    if (ws_size >= 96 * MB) {
        unsigned short* hsb  = (unsigned short*)ws;               // 16 MB (reused as attn out)
        unsigned short* wqkv = (unsigned short*)(ws + 16 * MB);   // 24 MB: Wq|Wk|Wv [6144][2048]
        unsigned short* wob  = (unsigned short*)(ws + 40 * MB);   //  8 MB
        unsigned short* qb   = (unsigned short*)(ws + 48 * MB);   // kb=+8M, vtb=+16M elems
        unsigned short* kb   = (unsigned short*)(ws + 64 * MB);
        unsigned short* vtb  = (unsigned short*)(ws + 80 * MB);
        unsigned short* aob  = hsb;
        unsigned short* wqb  = wqkv;
        unsigned short* wkb  = wqkv + 2048L * 2048;
        unsigned short* wvb  = wqkv + 2L * 2048 * 2048;

        cvt5<<<dim3(1024, 1, 5), 256, 0, stream>>>(
            hs, Wq, Wk, Wv, Wo,
            hsb, wqb, wkb, wvb, wob,
            (long)MTOT * HDIM / 8, (long)HDIM * HDIM / 8);
        gemm_p<0><<<dim3(32, 48), 256, 0, stream>>>(hsb, wqkv, bq, bk, bv, qb, rs);
        attn_fwd<<<256, 512, 0, stream>>>(qb, kb, vtb, aob);
        gemm_p<2><<<dim3(32, 16), 256, 0, stream>>>(aob, wob, bo, bo, bo, out, 1.0f);
    } else {
        // tighter layout: 88 MB; convert Wo into wqkv space after QKV GEMM
        unsigned short* hsb  = (unsigned short*)ws;               // 16 MB
        unsigned short* wqkv = (unsigned short*)(ws + 16 * MB);   // 24 MB
        unsigned short* qb   = (unsigned short*)(ws + 40 * MB);
        unsigned short* kb   = (unsigned short*)(ws + 56 * MB);
        unsigned short* vtb  = (unsigned short*)(ws + 72 * MB);
        unsigned short* aob  = hsb;

        cvt_bf16<<<2048, 256, 0, stream>>>(hs, hsb, (long)MTOT * HDIM / 8);
        cvt_bf16<<<2048, 256, 0, stream>>>(Wq, wqkv, (long)HDIM * HDIM / 8);
        cvt_bf16<<<2048, 256, 0, stream>>>(Wk, wqkv + 2048L * 2048, (long)HDIM * HDIM / 8);
        cvt_bf16<<<2048, 256, 0, stream>>>(Wv, wqkv + 2L * 2048 * 2048, (long)HDIM * HDIM / 8);
        gemm_p<0><<<dim3(32, 48), 256, 0, stream>>>(hsb, wqkv, bq, bk, bv, qb, rs);
        attn_fwd<<<256, 512, 0, stream>>>(qb, kb, vtb, aob);
        cvt_bf16<<<2048, 256, 0, stream>>>(Wo, wqkv, (long)HDIM * HDIM / 8);
        gemm_p<2><<<dim3(32, 16), 256, 0, stream>>>(aob, wqkv, bo, bo, bo, out, 1.0f);
    }
}